// Round 11
// baseline (6720.405 us; speedup 1.0000x reference)
//
#include <hip/hip_runtime.h>
#include <hip/hip_bf16.h>
#include <math.h>

// ConvLSTMClassifier on MI355X — lean 2-step trapezoid fusion, MFMA.
// gates[b,w,n] = bias[n] + sum_kx x[b,t,w+kx-1]*pxw[kx,n]
//              + sum_kx sum_ic h[b,w+kx-1,ic]*Bp[kx,n,ic],  n = g*128+ch.
// State: hc[b][w][ch] u32 = h(bf16 lo) | c(bf16 hi), packed (r10-proven).
// Each launch runs steps (t, t+1) for its M=64 owned rows:
//   step t: 66 halo rows (mo in [0,65], w = w0-1+mo) from S1 slab;
//     phase A (gates i,f): si,cf -> sc LDS (bf16|bf16);
//     phase B (gates g,o): h(t) -> S2 slab (aliases S1, barrier-protected),
//                          c(t) -> sc as FULL f32 (no mid-pair rounding).
//   step t+1: 64 owned rows (m, w = w0+m) from S2; si/cf in registers;
//     final h,c packed bf16 -> global (or pooled if LAST).
// LDS 52.3 KB -> 2 blocks/CU. Peak regs ~40 AGPR + ~70 VGPR < 128 (no spill).
// Block 512 thr / 8 waves (16-ch slice each, all 4 gates). grid (8,64)=512.
// 64 launches + fc_final.

constexpr int kB  = 64;
constexpr int kCH = 128;
constexpr int kH  = 128;
constexpr int kW  = 512;
constexpr int kNC = 10;

typedef __attribute__((ext_vector_type(8))) short short8v;
typedef __attribute__((ext_vector_type(4))) float float4v;

__device__ __forceinline__ float fsig(float v) {
    return 1.0f / (1.0f + __expf(-v));
}
__device__ __forceinline__ float ftanh(float v) {
    float e = __expf(2.0f * v);
    return 1.0f - 2.0f / (e + 1.0f);
}
__device__ __forceinline__ unsigned int pack2bf(float lo, float hi) {
    __hip_bfloat16 l = __float2bfloat16(lo);
    __hip_bfloat16 h = __float2bfloat16(hi);
    return (unsigned int)*reinterpret_cast<unsigned short*>(&l) |
           ((unsigned int)*reinterpret_cast<unsigned short*>(&h) << 16);
}
__device__ __forceinline__ float lo_bf(unsigned int u) {
    unsigned int t = u << 16;
    return *reinterpret_cast<float*>(&t);
}
__device__ __forceinline__ float hi_bf(unsigned int u) {
    unsigned int t = u & 0xffff0000u;
    return *reinterpret_cast<float*>(&t);
}

// ---------------------------------------------------------------------------
// Weight pack: Bp[kx][oc][ic] bf16, pxw[kx][oc] f32, pb[oc] f32.
// Also zeroes the pooled accumulator (ws is poisoned before timing).
// ---------------------------------------------------------------------------
__global__ __launch_bounds__(256) void pack_weights(
    const float* __restrict__ conv_w,  // [512][129][3][3]
    const float* __restrict__ conv_b,  // [512]
    short* __restrict__ Bp,            // [3][512][128]
    float* __restrict__ pxw,           // [3][512]
    float* __restrict__ pb,            // [512]
    float* __restrict__ pooled)        // [64][128]
{
    int idx = blockIdx.x * 256 + threadIdx.x;
    if (idx < 3 * 512 * 128) {
        int ic = idx & 127;
        int oc = (idx >> 7) & 511;
        int kx = idx >> 16;
        float v = conv_w[((oc * 129 + 1 + ic) * 3 + 1) * 3 + kx];
        __hip_bfloat16 hv = __float2bfloat16(v);
        Bp[idx] = *reinterpret_cast<short*>(&hv);
    }
    if (idx < 3 * 512) {
        int oc = idx & 511, kx = idx >> 9;
        pxw[idx] = conv_w[((oc * 129 + 0) * 3 + 1) * 3 + kx];
    }
    if (idx < 512) pb[idx] = conv_b[idx];
    if (idx < kB * kCH) pooled[idx] = 0.0f;
}

// ---------------------------------------------------------------------------
// GEMM for one gate pair (G0, G0+1): NMF m-frags from slab Sl.
// srow = mf*16 + ncol + kx. For NMF=5 srow can reach 81 (> slab rows) —
// those reads land inside this block's other LDS arrays (garbage) and feed
// ONLY discarded output rows (mo > 65); MFMA rows are independent. Safe.
// ---------------------------------------------------------------------------
template <int NMF, int G0>
__device__ __forceinline__ void gemm2(
    const short* __restrict__ Sl, const short* __restrict__ Bp,
    int ch, int krow, int ncol, bool skip, float4v (&acc)[NMF][2])
{
#pragma unroll
    for (int mf = 0; mf < NMF; ++mf) {
        acc[mf][0] = float4v{0.f, 0.f, 0.f, 0.f};
        acc[mf][1] = float4v{0.f, 0.f, 0.f, 0.f};
    }
    if (skip) return;
#pragma unroll
    for (int kx = 0; kx < 3; ++kx) {
#pragma unroll
        for (int ks = 0; ks < 4; ++ks) {
            short8v b0 = *reinterpret_cast<const short8v*>(
                Bp + ((kx * 512 + G0 * 128 + ch) * 128 + ks * 32 + krow * 8));
            short8v b1 = *reinterpret_cast<const short8v*>(
                Bp + ((kx * 512 + (G0 + 1) * 128 + ch) * 128 + ks * 32 + krow * 8));
#pragma unroll
            for (int mf = 0; mf < NMF; ++mf) {
                int srow = mf * 16 + ncol + kx;
                int slot = (ks * 4 + krow) ^ (srow & 7);
                short8v a = *reinterpret_cast<const short8v*>(
                    Sl + srow * 128 + slot * 8);
                acc[mf][0] = __builtin_amdgcn_mfma_f32_16x16x32_bf16(
                    a, b0, acc[mf][0], 0, 0, 0);
                acc[mf][1] = __builtin_amdgcn_mfma_f32_16x16x32_bf16(
                    a, b1, acc[mf][1], 0, 0, 0);
            }
        }
    }
}

// ---------------------------------------------------------------------------
template <bool FIRST, bool LAST>
__global__ __launch_bounds__(512) void lstm2(
    const float* __restrict__ x,            // [B][1][H][W]
    const short* __restrict__ Bp,           // [3][512][128]
    const float* __restrict__ pxw,          // [3][512]
    const float* __restrict__ pb,           // [512]
    const unsigned int* __restrict__ hcIn,  // [B][W][CH] packed h|c (t0-1)
    unsigned int* __restrict__ hcOut,       // [B][W][CH] packed h|c (t0+1)
    float* __restrict__ pooled,             // [B][CH]
    int t0)
{
    // Sbuf: step-t A-slab (h(t0-1), 68 rows, w = w0-2+row), then REUSED as
    // step-(t+1) A-slab (h(t0), 66 rows, w = w0-1+row). Barrier-protected.
    __shared__ alignas(16) short Sbuf[68 * 128];   // 17408 B
    __shared__ unsigned int sc[66 * 130];          // 34320 B si|cf -> c(f32)
    __shared__ float xs0[68], xs1[68];             // 544 B

    const int tid  = threadIdx.x;
    const int lane = tid & 63;
    const int wave = tid >> 6;          // 0..7 = 16-ch slice
    const int w0   = blockIdx.x * 64;
    const int b    = blockIdx.y;

    const int ncol = lane & 15;
    const int krow = lane >> 4;
    const int ch   = wave * 16 + ncol;  // 0..127

    const size_t gbase = (size_t)b * kW * kCH;

    // per-lane constants: bias + x-channel conv weights (all 4 gates)
    float wxk[4][3], bia[4];
#pragma unroll
    for (int g = 0; g < 4; ++g) {
        bia[g] = pb[g * 128 + ch];
#pragma unroll
        for (int kx = 0; kx < 3; ++kx)
            wxk[g][kx] = pxw[kx * 512 + g * 128 + ch];
    }

    // ---- staging: x rows t0, t0+1 (origin w0-2) + h(t0-1) slab ----
    const float* xb = x + ((size_t)b * kH + t0) * kW;
    for (int i = tid; i < 2 * 68; i += 512) {
        int s = (i < 68) ? 0 : 1;
        int j = (i < 68) ? i : i - 68;
        int w = w0 - 2 + j;
        float v = (w >= 0 && w < kW) ? xb[s * kW + w] : 0.0f;
        if (s == 0) xs0[j] = v; else xs1[j] = v;
    }
    if (!FIRST) {
        for (int i = tid; i < 68 * 16; i += 512) {
            int row = i >> 4, col = i & 15;
            int w = w0 - 2 + row;
            short8v v = {0, 0, 0, 0, 0, 0, 0, 0};
            if (w >= 0 && w < kW) {
                const uint4* p = reinterpret_cast<const uint4*>(
                    hcIn + gbase + (size_t)w * kCH + col * 8);
                uint4 a = p[0], d = p[1];
                v[0] = (short)(a.x & 0xffff); v[1] = (short)(a.y & 0xffff);
                v[2] = (short)(a.z & 0xffff); v[3] = (short)(a.w & 0xffff);
                v[4] = (short)(d.x & 0xffff); v[5] = (short)(d.y & 0xffff);
                v[6] = (short)(d.z & 0xffff); v[7] = (short)(d.w & 0xffff);
            }
            *reinterpret_cast<short8v*>(
                Sbuf + row * 128 + (col ^ (row & 7)) * 8) = v;
        }
    }
    __syncthreads();

    // ================= STEP t0: 66 rows (mo in [0,65], w = w0-1+mo) ========
    // phase A: gates i(0), f(1) -> si|cf to sc
    {
        float4v acc[5][2];
        gemm2<5, 0>(Sbuf, Bp, ch, krow, ncol, FIRST, acc);
#pragma unroll
        for (int mf = 0; mf < 5; ++mf) {
            unsigned int cu[4];
#pragma unroll
            for (int r = 0; r < 4; ++r) {
                int mo = mf * 16 + krow * 4 + r;
                int w = w0 - 1 + mo;
                cu[r] = (!FIRST && mo <= 65 && w >= 0 && w < kW)
                      ? hcIn[gbase + (size_t)w * kCH + ch] : 0u;
            }
#pragma unroll
            for (int r = 0; r < 4; ++r) {
                int mo = mf * 16 + krow * 4 + r;
                if (mo <= 65) {
                    float xm = xs0[mo], xc = xs0[mo + 1], xp = xs0[mo + 2];
                    float v0 = acc[mf][0][r] + bia[0] + xm * wxk[0][0] + xc * wxk[0][1] + xp * wxk[0][2];
                    float v1 = acc[mf][1][r] + bia[1] + xm * wxk[1][0] + xc * wxk[1][1] + xp * wxk[1][2];
                    float cprev = hi_bf(cu[r]);
                    float si = fsig(v0);
                    float cf = fsig(v1) * cprev;
                    sc[mo * 130 + ch] = pack2bf(si, cf);
                }
            }
        }
    }
    // phase B: gates g(2), o(3) -> h(t0) into S2 (= Sbuf, re-purposed), c->sc
    {
        float4v acc[5][2];
        gemm2<5, 2>(Sbuf, Bp, ch, krow, ncol, FIRST, acc);
        __syncthreads();  // ALL waves done reading S1 before S2 overwrites
#pragma unroll
        for (int mf = 0; mf < 5; ++mf) {
#pragma unroll
            for (int r = 0; r < 4; ++r) {
                int mo = mf * 16 + krow * 4 + r;
                if (mo <= 65) {
                    int w = w0 - 1 + mo;
                    bool ok = (w >= 0) && (w < kW);
                    float xm = xs0[mo], xc = xs0[mo + 1], xp = xs0[mo + 2];
                    float v2 = acc[mf][0][r] + bia[2] + xm * wxk[2][0] + xc * wxk[2][1] + xp * wxk[2][2];
                    float v3 = acc[mf][1][r] + bia[3] + xm * wxk[3][0] + xc * wxk[3][1] + xp * wxk[3][2];
                    unsigned int u = sc[mo * 130 + ch];
                    float si = lo_bf(u), cf = hi_bf(u);
                    float cn = cf + si * ftanh(v2);
                    float hn = fsig(v3) * ftanh(cn);
                    __hip_bfloat16 hv = __float2bfloat16(ok ? hn : 0.0f);
                    Sbuf[mo * 128 + ((ch >> 3) ^ (mo & 7)) * 8 + (ch & 7)] =
                        *reinterpret_cast<short*>(&hv);
                    sc[mo * 130 + ch] = *reinterpret_cast<unsigned int*>(&cn);
                }
            }
        }
    }
    __syncthreads();  // S2 + c(t0) complete, visible to all waves

    // ================= STEP t0+1: 64 rows (m in [0,63], w = w0+m) ==========
    float si2[4][4], cf2[4][4];
    // phase A: gates i,f — si/cf stay in registers
    {
        float4v acc[4][2];
        gemm2<4, 0>(Sbuf, Bp, ch, krow, ncol, false, acc);
#pragma unroll
        for (int mf = 0; mf < 4; ++mf) {
#pragma unroll
            for (int r = 0; r < 4; ++r) {
                int m = mf * 16 + krow * 4 + r;
                float xm = xs1[m + 1], xc = xs1[m + 2], xp = xs1[m + 3];
                float v0 = acc[mf][0][r] + bia[0] + xm * wxk[0][0] + xc * wxk[0][1] + xp * wxk[0][2];
                float v1 = acc[mf][1][r] + bia[1] + xm * wxk[1][0] + xc * wxk[1][1] + xp * wxk[1][2];
                unsigned int cbits = sc[(m + 1) * 130 + ch];  // c(t0), full f32
                float cprev = *reinterpret_cast<float*>(&cbits);
                si2[mf][r] = fsig(v0);
                cf2[mf][r] = fsig(v1) * cprev;
            }
        }
    }
    // phase B: gates g,o -> final state to global (or pooling)
    {
        float4v acc[4][2];
        gemm2<4, 2>(Sbuf, Bp, ch, krow, ncol, false, acc);
        float psum = 0.0f;
#pragma unroll
        for (int mf = 0; mf < 4; ++mf) {
#pragma unroll
            for (int r = 0; r < 4; ++r) {
                int m = mf * 16 + krow * 4 + r;
                float xm = xs1[m + 1], xc = xs1[m + 2], xp = xs1[m + 3];
                float v2 = acc[mf][0][r] + bia[2] + xm * wxk[2][0] + xc * wxk[2][1] + xp * wxk[2][2];
                float v3 = acc[mf][1][r] + bia[3] + xm * wxk[3][0] + xc * wxk[3][1] + xp * wxk[3][2];
                float cn = cf2[mf][r] + si2[mf][r] * ftanh(v2);
                float hn = fsig(v3) * ftanh(cn);
                if (LAST) {
                    psum += hn;
                } else {
                    hcOut[gbase + (size_t)(w0 + m) * kCH + ch] = pack2bf(hn, cn);
                }
            }
        }
        if (LAST) {
            psum += __shfl_xor(psum, 16, 64);
            psum += __shfl_xor(psum, 32, 64);
            if (krow == 0) atomicAdd(&pooled[b * kCH + ch], psum);
        }
    }
}

// ---------------------------------------------------------------------------
// Final FC from pooled sums. grid = B, block = 64.
// ---------------------------------------------------------------------------
__global__ __launch_bounds__(64) void fc_final(
    const float* __restrict__ pooled,  // [B][CH] raw sums over W
    const float* __restrict__ fc_w,    // [NC][CH]
    const float* __restrict__ fc_b,    // [NC]
    float* __restrict__ out)           // [B][NC]
{
    int b = blockIdx.x, nc = threadIdx.x;
    if (nc < kNC) {
        float s = 0.0f;
        for (int k = 0; k < kCH; ++k)
            s = fmaf(pooled[b * kCH + k], fc_w[nc * kCH + k], s);
        out[b * kNC + nc] = fc_b[nc] + s * (1.0f / kW);
    }
}

// ---------------------------------------------------------------------------
extern "C" void kernel_launch(void* const* d_in, const int* in_sizes, int n_in,
                              void* d_out, int out_size, void* d_ws, size_t ws_size,
                              hipStream_t stream) {
    const float* x      = (const float*)d_in[0];
    const float* conv_w = (const float*)d_in[1];
    const float* conv_b = (const float*)d_in[2];
    const float* fc_w   = (const float*)d_in[3];
    const float* fc_b   = (const float*)d_in[4];
    float* out = (float*)d_out;

    const size_t stateN = (size_t)kB * kW * kCH;  // 4,194,304
    unsigned int* hcA   = (unsigned int*)d_ws;
    unsigned int* hcB   = hcA + stateN;
    short* Bp           = (short*)(hcB + stateN);
    float* pxw          = (float*)(Bp + 3 * 512 * 128);
    float* pb           = pxw + 3 * 512;
    float* pooled       = pb + 512;  // [64][128]

    pack_weights<<<768, 256, 0, stream>>>(conv_w, conv_b, Bp, pxw, pb, pooled);

    dim3 grid(kW / 64, kB);
    dim3 block(512);
    // pair k covers steps (2k, 2k+1): out(k) = k even ? hcB : hcA,
    // in(k) = out(k-1).
    lstm2<true, false><<<grid, block, 0, stream>>>(
        x, Bp, pxw, pb, hcA /*unused*/, hcB, pooled, 0);
    for (int k = 1; k < 63; ++k) {
        const unsigned int* hi = (k & 1) ? hcB : hcA;
        unsigned int*       ho = (k & 1) ? hcA : hcB;
        lstm2<false, false><<<grid, block, 0, stream>>>(
            x, Bp, pxw, pb, hi, ho, pooled, 2 * k);
    }
    // k = 63 (odd): in = out(62) = hcB; outputs pooled only.
    lstm2<false, true><<<grid, block, 0, stream>>>(
        x, Bp, pxw, pb, hcB, hcA, pooled, 126);

    fc_final<<<kB, 64, 0, stream>>>(pooled, fc_w, fc_b, out);
}

// Round 12
// 4545.782 us; speedup vs baseline: 1.4784x; 1.4784x over previous
//
#include <hip/hip_runtime.h>
#include <hip/hip_bf16.h>
#include <math.h>

// ConvLSTMClassifier on MI355X — per-step MFMA, M=128 blocks, B-weights
// pipelined through triple-buffered LDS.
// gates[b,w,n] = bias[n] + sum_kx x[b,t,w+kx-1]*pxw[kx,n]
//              + sum_kx sum_ic h[b,w+kx-1,ic]*Bp[kx,n,ic],  n = g*128+ch.
// State: hc[b][w][ch] u32 = h(bf16 lo) | c(bf16 hi)  (r10-proven).
// Block: 1024 thr / 16 waves = 4/SIMD; tile M=128 (w rows) x N=512.
// Wave (chsl = wave&7, mgrp = wave>>3): 16-ch slice x 4 gates x 4 m-frags.
// B: 12 stages of (kx,ks) 32KB each -> 3-buffer LDS pipeline, 1 barrier/iter:
//   iter s: compute buf[s%3] | commit stage s+2 | issue stage s+3.
// LDS: A-slab 33.3KB + 3x32KB B + xs = 132KB -> 1 block/CU.
// Per-CU B traffic halves vs r10 (M=128 per fetch); B-read latency hidden.
// grid (4,64) = 256 blocks. 128 launches + fc_final.

constexpr int kB  = 64;
constexpr int kCH = 128;
constexpr int kH  = 128;
constexpr int kW  = 512;
constexpr int kNC = 10;

typedef __attribute__((ext_vector_type(8))) short short8v;
typedef __attribute__((ext_vector_type(4))) float float4v;

__device__ __forceinline__ float fsig(float v) {
    return 1.0f / (1.0f + __expf(-v));
}
__device__ __forceinline__ float ftanh(float v) {
    float e = __expf(2.0f * v);
    return 1.0f - 2.0f / (e + 1.0f);
}
__device__ __forceinline__ unsigned int pack2bf(float lo, float hi) {
    __hip_bfloat16 l = __float2bfloat16(lo);
    __hip_bfloat16 h = __float2bfloat16(hi);
    return (unsigned int)*reinterpret_cast<unsigned short*>(&l) |
           ((unsigned int)*reinterpret_cast<unsigned short*>(&h) << 16);
}
__device__ __forceinline__ float hi_bf(unsigned int u) {
    unsigned int t = u & 0xffff0000u;
    return *reinterpret_cast<float*>(&t);
}

// ---------------------------------------------------------------------------
// Weight pack: Bp[kx][oc][ic] bf16, pxw[kx][oc] f32, pb[oc] f32.
// Also zeroes the pooled accumulator (ws is poisoned before timing).
// ---------------------------------------------------------------------------
__global__ __launch_bounds__(256) void pack_weights(
    const float* __restrict__ conv_w,  // [512][129][3][3]
    const float* __restrict__ conv_b,  // [512]
    short* __restrict__ Bp,            // [3][512][128]
    float* __restrict__ pxw,           // [3][512]
    float* __restrict__ pb,            // [512]
    float* __restrict__ pooled)        // [64][128]
{
    int idx = blockIdx.x * 256 + threadIdx.x;
    if (idx < 3 * 512 * 128) {
        int ic = idx & 127;
        int oc = (idx >> 7) & 511;
        int kx = idx >> 16;
        float v = conv_w[((oc * 129 + 1 + ic) * 3 + 1) * 3 + kx];
        __hip_bfloat16 hv = __float2bfloat16(v);
        Bp[idx] = *reinterpret_cast<short*>(&hv);
    }
    if (idx < 3 * 512) {
        int oc = idx & 511, kx = idx >> 9;
        pxw[idx] = conv_w[((oc * 129 + 0) * 3 + 1) * 3 + kx];
    }
    if (idx < 512) pb[idx] = conv_b[idx];
    if (idx < kB * kCH) pooled[idx] = 0.0f;
}

// ---------------------------------------------------------------------------
// One LSTM step. grid = (4 wtiles, 64 b), block = 1024 (16 waves).
// ---------------------------------------------------------------------------
template <bool FIRST, bool LAST>
__global__ __launch_bounds__(1024, 4) void lstm_step(
    const float* __restrict__ x,            // [B][1][H][W]
    const short* __restrict__ Bp,           // [3][512][128]
    const float* __restrict__ pxw,          // [3][512]
    const float* __restrict__ pb,           // [512]
    const unsigned int* __restrict__ hcIn,  // [B][W][CH] packed h|c
    unsigned int* __restrict__ hcOut,       // [B][W][CH] packed h|c
    float* __restrict__ pooled,             // [B][CH]
    int t)
{
    __shared__ alignas(16) short S[130 * 128];      // h slab w0-1..w0+128, swz
    __shared__ alignas(16) short Bb[3][512 * 32];   // 3 x 32KB B stages
    __shared__ float xs[130];

    const int tid  = threadIdx.x;
    const int lane = tid & 63;
    const int wave = tid >> 6;          // 0..15
    const int w0   = blockIdx.x * 128;
    const int b    = blockIdx.y;

    const int ncol = lane & 15;
    const int krow = lane >> 4;
    const int chsl = wave & 7;
    const int mgrp = wave >> 3;         // 0/1 -> m rows 0-63 / 64-127
    const int ch   = chsl * 16 + ncol;  // 0..127
    const int mbase = mgrp * 64;

    const size_t gbase = (size_t)b * kW * kCH;

    // B-stage pipeline helpers. Stage s = (kx = s>>2, ks = s&3), 32KB:
    // thread t owns row n = t>>1, half h = t&1 (32B of the 64B k-row).
    const int sn = tid >> 1, sh = tid & 1;
    const int ssw = (sn ^ (sn >> 2)) & 3;   // write-side slot swizzle
    uint4 br0, br1;
    const uint4* bsrc0 = reinterpret_cast<const uint4*>(
        Bp + ((size_t)sn * 128 + sh * 16));  // + (kx*512*128 + ks*32) shorts

#define B_ISSUE(stage)                                                         \
    {                                                                          \
        int kx_ = (stage) >> 2, ks_ = (stage) & 3;                             \
        const uint4* p_ = bsrc0 + ((size_t)kx_ * 512 * 128 + ks_ * 32) / 8;    \
        br0 = p_[0];                                                           \
        br1 = p_[1];                                                           \
    }
#define B_COMMIT(buf)                                                          \
    {                                                                          \
        uint4* row_ = reinterpret_cast<uint4*>(&Bb[buf][sn * 32]);             \
        row_[(2 * sh) ^ ssw] = br0;                                            \
        row_[(2 * sh + 1) ^ ssw] = br1;                                       \
    }

    // ---- staging: x strip + h slab ----
    for (int i = tid; i < 130; i += 1024) {
        int w = w0 - 1 + i;
        xs[i] = (w >= 0 && w < kW)
              ? x[((size_t)b * kH + t) * kW + w] : 0.0f;
    }
    if (!FIRST) {
        for (int i = tid; i < 130 * 16; i += 1024) {
            int row = i >> 4, col = i & 15;
            int w = w0 - 1 + row;
            short8v v = {0, 0, 0, 0, 0, 0, 0, 0};
            if (w >= 0 && w < kW) {
                const uint4* p = reinterpret_cast<const uint4*>(
                    hcIn + gbase + (size_t)w * kCH + col * 8);
                uint4 a = p[0], d = p[1];
                v[0] = (short)(a.x & 0xffff); v[1] = (short)(a.y & 0xffff);
                v[2] = (short)(a.z & 0xffff); v[3] = (short)(a.w & 0xffff);
                v[4] = (short)(d.x & 0xffff); v[5] = (short)(d.y & 0xffff);
                v[6] = (short)(d.z & 0xffff); v[7] = (short)(d.w & 0xffff);
            }
            *reinterpret_cast<short8v*>(
                S + row * 128 + (col ^ (row & 7)) * 8) = v;
        }
    }

    // ---- GEMM with triple-buffered B pipeline ----
    float4v acc[4][4];
#pragma unroll
    for (int mf = 0; mf < 4; ++mf)
#pragma unroll
        for (int g = 0; g < 4; ++g)
            acc[mf][g] = float4v{0.f, 0.f, 0.f, 0.f};

    if (!FIRST) {
        B_ISSUE(0) B_COMMIT(0)
        B_ISSUE(1) B_COMMIT(1)
        B_ISSUE(2)
        __syncthreads();  // A-slab + Bb[0]/Bb[1] ready; Bb[2] in regs

        const int rsw[4] = {                    // read-side slot per gate
            (krow ^ (((0 * 128 + ch) ^ ((0 * 128 + ch) >> 2)) & 3)) * 8,
            (krow ^ (((1 * 128 + ch) ^ ((1 * 128 + ch) >> 2)) & 3)) * 8,
            (krow ^ (((2 * 128 + ch) ^ ((2 * 128 + ch) >> 2)) & 3)) * 8,
            (krow ^ (((3 * 128 + ch) ^ ((3 * 128 + ch) >> 2)) & 3)) * 8};

#pragma unroll
        for (int it = 0; it < 12; ++it) {
            const int kx = it >> 2, ks = it & 3;
            const short* Bcur = Bb[it % 3];
            short8v bfr[4];
#pragma unroll
            for (int g = 0; g < 4; ++g)
                bfr[g] = *reinterpret_cast<const short8v*>(
                    Bcur + (g * 128 + ch) * 32 + rsw[g]);
#pragma unroll
            for (int mf = 0; mf < 4; ++mf) {
                int srow = mbase + mf * 16 + ncol + kx;
                int slot = (ks * 4 + krow) ^ (srow & 7);
                short8v afr = *reinterpret_cast<const short8v*>(
                    S + srow * 128 + slot * 8);
#pragma unroll
                for (int g = 0; g < 4; ++g)
                    acc[mf][g] = __builtin_amdgcn_mfma_f32_16x16x32_bf16(
                        afr, bfr[g], acc[mf][g], 0, 0, 0);
            }
            if (it <= 9) { B_COMMIT((it + 2) % 3) }
            if (it <= 8) { B_ISSUE(it + 3) }
            __syncthreads();
        }
    } else {
        __syncthreads();  // xs visibility
    }

    // ---- epilogue (r10-identical) ----
    float wxk[4][3], bia[4];
#pragma unroll
    for (int g = 0; g < 4; ++g) {
        bia[g] = pb[g * 128 + ch];
#pragma unroll
        for (int kx = 0; kx < 3; ++kx)
            wxk[g][kx] = pxw[kx * 512 + g * 128 + ch];
    }

    float psum = 0.0f;
#pragma unroll
    for (int mf = 0; mf < 4; ++mf) {
        unsigned int cu[4];
        if (!FIRST) {
#pragma unroll
            for (int r = 0; r < 4; ++r) {
                int m = mbase + mf * 16 + krow * 4 + r;
                cu[r] = hcIn[gbase + (size_t)(w0 + m) * kCH + ch];
            }
        }
#pragma unroll
        for (int r = 0; r < 4; ++r) {
            int m = mbase + mf * 16 + krow * 4 + r;
            float xm = xs[m], xc = xs[m + 1], xp = xs[m + 2];
            float v0 = acc[mf][0][r] + bia[0] + xm * wxk[0][0] + xc * wxk[0][1] + xp * wxk[0][2];
            float v1 = acc[mf][1][r] + bia[1] + xm * wxk[1][0] + xc * wxk[1][1] + xp * wxk[1][2];
            float v2 = acc[mf][2][r] + bia[2] + xm * wxk[2][0] + xc * wxk[2][1] + xp * wxk[2][2];
            float v3 = acc[mf][3][r] + bia[3] + xm * wxk[3][0] + xc * wxk[3][1] + xp * wxk[3][2];
            float cprev = FIRST ? 0.0f : hi_bf(cu[r]);
            float si = fsig(v0);
            float sf = fsig(v1);
            float tg = ftanh(v2);
            float so = fsig(v3);
            float cn = sf * cprev + si * tg;
            float hn = so * ftanh(cn);
            if (LAST) {
                psum += hn;
            } else {
                hcOut[gbase + (size_t)(w0 + m) * kCH + ch] = pack2bf(hn, cn);
            }
        }
    }

    if (LAST) {
        psum += __shfl_xor(psum, 16, 64);
        psum += __shfl_xor(psum, 32, 64);
        if (krow == 0) atomicAdd(&pooled[b * kCH + ch], psum);
    }
#undef B_ISSUE
#undef B_COMMIT
}

// ---------------------------------------------------------------------------
// Final FC from pooled sums. grid = B, block = 64.
// ---------------------------------------------------------------------------
__global__ __launch_bounds__(64) void fc_final(
    const float* __restrict__ pooled,  // [B][CH] raw sums over W
    const float* __restrict__ fc_w,    // [NC][CH]
    const float* __restrict__ fc_b,    // [NC]
    float* __restrict__ out)           // [B][NC]
{
    int b = blockIdx.x, nc = threadIdx.x;
    if (nc < kNC) {
        float s = 0.0f;
        for (int k = 0; k < kCH; ++k)
            s = fmaf(pooled[b * kCH + k], fc_w[nc * kCH + k], s);
        out[b * kNC + nc] = fc_b[nc] + s * (1.0f / kW);
    }
}

// ---------------------------------------------------------------------------
extern "C" void kernel_launch(void* const* d_in, const int* in_sizes, int n_in,
                              void* d_out, int out_size, void* d_ws, size_t ws_size,
                              hipStream_t stream) {
    const float* x      = (const float*)d_in[0];
    const float* conv_w = (const float*)d_in[1];
    const float* conv_b = (const float*)d_in[2];
    const float* fc_w   = (const float*)d_in[3];
    const float* fc_b   = (const float*)d_in[4];
    float* out = (float*)d_out;

    const size_t stateN = (size_t)kB * kW * kCH;  // 4,194,304
    unsigned int* hcA   = (unsigned int*)d_ws;
    unsigned int* hcB   = hcA + stateN;
    short* Bp           = (short*)(hcB + stateN);
    float* pxw          = (float*)(Bp + 3 * 512 * 128);
    float* pb           = pxw + 3 * 512;
    float* pooled       = pb + 512;  // [64][128]

    pack_weights<<<768, 256, 0, stream>>>(conv_w, conv_b, Bp, pxw, pb, pooled);

    dim3 grid(kW / 128, kB);
    dim3 block(1024);
    // write(t) = t even ? hcB : hcA; read(t) = write(t-1).
    lstm_step<true, false><<<grid, block, 0, stream>>>(
        x, Bp, pxw, pb, hcA, hcB, pooled, 0);
    for (int t = 1; t < kH - 1; ++t) {
        const unsigned int* hi = (t & 1) ? hcB : hcA;
        unsigned int*       ho = (t & 1) ? hcA : hcB;
        lstm_step<false, false><<<grid, block, 0, stream>>>(
            x, Bp, pxw, pb, hi, ho, pooled, t);
    }
    // t = 127 (odd): reads write(126) = hcB; outputs pooled only.
    lstm_step<false, true><<<grid, block, 0, stream>>>(
        x, Bp, pxw, pb, hcB, hcA, pooled, 127);

    fc_final<<<kB, 64, 0, stream>>>(pooled, fc_w, fc_b, out);
}

// Round 13
// 3512.999 us; speedup vs baseline: 1.9130x; 1.2940x over previous
//
#include <hip/hip_runtime.h>
#include <hip/hip_bf16.h>
#include <math.h>

// ConvLSTMClassifier on MI355X — per-step MFMA, 4 blocks/CU, B via
// global_load_lds ping-pong pipeline.
// gates[b,w,n] = bias[n] + sum_kx x[b,t,w+kx-1]*pxw[kx,n]
//              + sum_kx sum_ic h[b,w+kx-1,ic]*Bp[kx,n,ic],  n = g*128+ch.
// State: hc[b][w][ch] u32 = h(bf16 lo) | c(bf16 hi)  (r10-proven).
// Block: 256 thr / 4 waves; tile M=64 (w rows) x N=256 (4 gates x 64 ch,
// ch-half selected by blockIdx.y). grid (8, 2, 64) = 1024 blocks = 4/CU.
// B pipeline: 24 stages of (kx,ks,gate-pair) 8KB; 2-buffer ping-pong;
// stage s+1 issued (global_load_lds, width 16) at top of iter s; the
// vmcnt(0)+barrier drain is hidden by the 3 co-resident sibling blocks.
// LDS layout: linear dest + inverse-swizzled global source + swizzled read
// (slot kk = sl ^ ((rr^(rr>>2))&3)) -> bank-uniform ds_read_b128.
// LDS 33.2 KB/block; regs ~64 acc + ~50 VGPR -> 4 waves/SIMD.

constexpr int kB  = 64;
constexpr int kCH = 128;
constexpr int kH  = 128;
constexpr int kW  = 512;
constexpr int kNC = 10;

typedef __attribute__((ext_vector_type(8))) short short8v;
typedef __attribute__((ext_vector_type(4))) float float4v;

__device__ __forceinline__ float fsig(float v) {
    return 1.0f / (1.0f + __expf(-v));
}
__device__ __forceinline__ float ftanh(float v) {
    float e = __expf(2.0f * v);
    return 1.0f - 2.0f / (e + 1.0f);
}
__device__ __forceinline__ unsigned int pack2bf(float lo, float hi) {
    __hip_bfloat16 l = __float2bfloat16(lo);
    __hip_bfloat16 h = __float2bfloat16(hi);
    return (unsigned int)*reinterpret_cast<unsigned short*>(&l) |
           ((unsigned int)*reinterpret_cast<unsigned short*>(&h) << 16);
}
__device__ __forceinline__ float hi_bf(unsigned int u) {
    unsigned int t = u & 0xffff0000u;
    return *reinterpret_cast<float*>(&t);
}

// ---------------------------------------------------------------------------
// Weight pack: Bp[kx][oc][ic] bf16, pxw[kx][oc] f32, pb[oc] f32.
// Also zeroes the pooled accumulator (ws is poisoned before timing).
// ---------------------------------------------------------------------------
__global__ __launch_bounds__(256) void pack_weights(
    const float* __restrict__ conv_w,  // [512][129][3][3]
    const float* __restrict__ conv_b,  // [512]
    short* __restrict__ Bp,            // [3][512][128]
    float* __restrict__ pxw,           // [3][512]
    float* __restrict__ pb,            // [512]
    float* __restrict__ pooled)        // [64][128]
{
    int idx = blockIdx.x * 256 + threadIdx.x;
    if (idx < 3 * 512 * 128) {
        int ic = idx & 127;
        int oc = (idx >> 7) & 511;
        int kx = idx >> 16;
        float v = conv_w[((oc * 129 + 1 + ic) * 3 + 1) * 3 + kx];
        __hip_bfloat16 hv = __float2bfloat16(v);
        Bp[idx] = *reinterpret_cast<short*>(&hv);
    }
    if (idx < 3 * 512) {
        int oc = idx & 511, kx = idx >> 9;
        pxw[idx] = conv_w[((oc * 129 + 0) * 3 + 1) * 3 + kx];
    }
    if (idx < 512) pb[idx] = conv_b[idx];
    if (idx < kB * kCH) pooled[idx] = 0.0f;
}

// ---------------------------------------------------------------------------
// One LSTM step. grid = (8 wtiles, 2 cht, 64 b), block = 256 (4 waves).
// ---------------------------------------------------------------------------
template <bool FIRST, bool LAST>
__global__ __launch_bounds__(256, 4) void lstm_step(
    const float* __restrict__ x,            // [B][1][H][W]
    const short* __restrict__ Bp,           // [3][512][128]
    const float* __restrict__ pxw,          // [3][512]
    const float* __restrict__ pb,           // [512]
    const unsigned int* __restrict__ hcIn,  // [B][W][CH] packed h|c
    unsigned int* __restrict__ hcOut,       // [B][W][CH] packed h|c
    float* __restrict__ pooled,             // [B][CH]
    int t)
{
    __shared__ alignas(16) short S[66 * 128];     // h slab, swizzled (16.9 KB)
    __shared__ alignas(16) short Bb[2][128 * 32]; // B ping-pong (2 x 8 KB)
    __shared__ float xs[66];

    const int tid  = threadIdx.x;
    const int lane = tid & 63;
    const int wave = tid >> 6;          // 0..3 = 16-ch slice within cht-half
    const int w0   = blockIdx.x * 64;
    const int cht  = blockIdx.y;        // ch-half
    const int b    = blockIdx.z;

    const int ncol = lane & 15;
    const int krow = lane >> 4;
    const int ch   = cht * 64 + wave * 16 + ncol;  // 0..127

    const size_t gbase = (size_t)b * kW * kCH;

    // gll source bases (shorts, at kx=ks=p=0): stage row rr, 16B slot sl.
    // LDS is written LINEARLY (lane*16B); the k-slot permutation kk is baked
    // into the per-lane GLOBAL address (inverse of the read-side swizzle).
    int bsrc[2], ldst[2];
#pragma unroll
    for (int cc = 0; cc < 2; ++cc) {
        int rr = wave * 32 + cc * 16 + (lane >> 2);
        int sl = lane & 3;
        int kk = sl ^ ((rr ^ (rr >> 2)) & 3);
        int n0 = (rr >> 6) * 128 + cht * 64 + (rr & 63);  // +p*256 rows later
        bsrc[cc] = n0 * 128 + kk * 8;       // shorts
        ldst[cc] = (wave * 2 + cc) * 512;   // shorts (1 KB per wave-chunk)
    }

#define B_ISSUE(OFF, BUF)                                                      \
    {                                                                          \
        __builtin_amdgcn_global_load_lds(                                      \
            (const unsigned int*)(Bp + bsrc[0] + (OFF)),                       \
            (unsigned int*)(&Bb[BUF][ldst[0]]), 16, 0, 0);                     \
        __builtin_amdgcn_global_load_lds(                                      \
            (const unsigned int*)(Bp + bsrc[1] + (OFF)),                       \
            (unsigned int*)(&Bb[BUF][ldst[1]]), 16, 0, 0);                     \
    }

    // ---- staging: x strip + h slab; prologue B stage 0 ----
    for (int i = tid; i < 66; i += 256) {
        int w = w0 - 1 + i;
        xs[i] = (w >= 0 && w < kW)
              ? x[((size_t)b * kH + t) * kW + w] : 0.0f;
    }
    if (!FIRST) {
        for (int i = tid; i < 66 * 16; i += 256) {
            int row = i >> 4, col = i & 15;
            int w = w0 - 1 + row;
            short8v v = {0, 0, 0, 0, 0, 0, 0, 0};
            if (w >= 0 && w < kW) {
                const uint4* p = reinterpret_cast<const uint4*>(
                    hcIn + gbase + (size_t)w * kCH + col * 8);
                uint4 a = p[0], d = p[1];
                v[0] = (short)(a.x & 0xffff); v[1] = (short)(a.y & 0xffff);
                v[2] = (short)(a.z & 0xffff); v[3] = (short)(a.w & 0xffff);
                v[4] = (short)(d.x & 0xffff); v[5] = (short)(d.y & 0xffff);
                v[6] = (short)(d.z & 0xffff); v[7] = (short)(d.w & 0xffff);
            }
            *reinterpret_cast<short8v*>(
                S + row * 128 + (col ^ (row & 7)) * 8) = v;
        }
        B_ISSUE(0, 0)  // stage (kx=0, ks=0, gates 0/1) -> buf0
    }
    __syncthreads();

    float4v acc[4][4];  // [mfrag][gate]
#pragma unroll
    for (int mf = 0; mf < 4; ++mf)
#pragma unroll
        for (int g = 0; g < 4; ++g)
            acc[mf][g] = float4v{0.f, 0.f, 0.f, 0.f};

    if (!FIRST) {
        const int rswz  = (ncol ^ (ncol >> 2)) & 3;
        const int roff0 = (wave * 16 + ncol) * 32 + (krow ^ rswz) * 8;
        const int roff1 = roff0 + 64 * 32;
        short8v afr[4];

#pragma unroll
        for (int kq = 0; kq < 12; ++kq) {
            const int kx = kq >> 2, ks = kq & 3;
            // iter s = 2kq: consume buf0 (gates 0,1); issue (kq, p=1) -> buf1
            B_ISSUE(kx * 65536 + ks * 32 + 32768, 1)
#pragma unroll
            for (int mf = 0; mf < 4; ++mf) {
                int srow = mf * 16 + ncol + kx;
                int slot = (ks * 4 + krow) ^ (srow & 7);
                afr[mf] = *reinterpret_cast<const short8v*>(
                    S + srow * 128 + slot * 8);
            }
            {
                short8v bv0 = *reinterpret_cast<const short8v*>(Bb[0] + roff0);
                short8v bv1 = *reinterpret_cast<const short8v*>(Bb[0] + roff1);
#pragma unroll
                for (int mf = 0; mf < 4; ++mf) {
                    acc[mf][0] = __builtin_amdgcn_mfma_f32_16x16x32_bf16(
                        afr[mf], bv0, acc[mf][0], 0, 0, 0);
                    acc[mf][1] = __builtin_amdgcn_mfma_f32_16x16x32_bf16(
                        afr[mf], bv1, acc[mf][1], 0, 0, 0);
                }
            }
            __syncthreads();
            // iter s = 2kq+1: consume buf1 (gates 2,3); issue (kq+1, p=0)
            if (kq < 11) {
                const int kx2 = (kq + 1) >> 2, ks2 = (kq + 1) & 3;
                B_ISSUE(kx2 * 65536 + ks2 * 32, 0)
            }
            {
                short8v bv2 = *reinterpret_cast<const short8v*>(Bb[1] + roff0);
                short8v bv3 = *reinterpret_cast<const short8v*>(Bb[1] + roff1);
#pragma unroll
                for (int mf = 0; mf < 4; ++mf) {
                    acc[mf][2] = __builtin_amdgcn_mfma_f32_16x16x32_bf16(
                        afr[mf], bv2, acc[mf][2], 0, 0, 0);
                    acc[mf][3] = __builtin_amdgcn_mfma_f32_16x16x32_bf16(
                        afr[mf], bv3, acc[mf][3], 0, 0, 0);
                }
            }
            __syncthreads();
        }
    }
#undef B_ISSUE

    // ---- epilogue (r10-identical math) ----
    float wxk[4][3], bia[4];
#pragma unroll
    for (int g = 0; g < 4; ++g) {
        bia[g] = pb[g * 128 + ch];
#pragma unroll
        for (int kx = 0; kx < 3; ++kx)
            wxk[g][kx] = pxw[kx * 512 + g * 128 + ch];
    }

    float psum = 0.0f;
#pragma unroll
    for (int mf = 0; mf < 4; ++mf) {
        unsigned int cu[4];
        if (!FIRST) {
#pragma unroll
            for (int r = 0; r < 4; ++r) {
                int m = mf * 16 + krow * 4 + r;
                cu[r] = hcIn[gbase + (size_t)(w0 + m) * kCH + ch];
            }
        }
#pragma unroll
        for (int r = 0; r < 4; ++r) {
            int m = mf * 16 + krow * 4 + r;
            float xm = xs[m], xc = xs[m + 1], xp = xs[m + 2];
            float v0 = acc[mf][0][r] + bia[0] + xm * wxk[0][0] + xc * wxk[0][1] + xp * wxk[0][2];
            float v1 = acc[mf][1][r] + bia[1] + xm * wxk[1][0] + xc * wxk[1][1] + xp * wxk[1][2];
            float v2 = acc[mf][2][r] + bia[2] + xm * wxk[2][0] + xc * wxk[2][1] + xp * wxk[2][2];
            float v3 = acc[mf][3][r] + bia[3] + xm * wxk[3][0] + xc * wxk[3][1] + xp * wxk[3][2];
            float cprev = FIRST ? 0.0f : hi_bf(cu[r]);
            float si = fsig(v0);
            float sf = fsig(v1);
            float tg = ftanh(v2);
            float so = fsig(v3);
            float cn = sf * cprev + si * tg;
            float hn = so * ftanh(cn);
            if (LAST) {
                psum += hn;
            } else {
                hcOut[gbase + (size_t)(w0 + m) * kCH + ch] = pack2bf(hn, cn);
            }
        }
    }

    if (LAST) {
        psum += __shfl_xor(psum, 16, 64);
        psum += __shfl_xor(psum, 32, 64);
        if (krow == 0) atomicAdd(&pooled[b * kCH + ch], psum);
    }
}

// ---------------------------------------------------------------------------
// Final FC from pooled sums. grid = B, block = 64.
// ---------------------------------------------------------------------------
__global__ __launch_bounds__(64) void fc_final(
    const float* __restrict__ pooled,  // [B][CH] raw sums over W
    const float* __restrict__ fc_w,    // [NC][CH]
    const float* __restrict__ fc_b,    // [NC]
    float* __restrict__ out)           // [B][NC]
{
    int b = blockIdx.x, nc = threadIdx.x;
    if (nc < kNC) {
        float s = 0.0f;
        for (int k = 0; k < kCH; ++k)
            s = fmaf(pooled[b * kCH + k], fc_w[nc * kCH + k], s);
        out[b * kNC + nc] = fc_b[nc] + s * (1.0f / kW);
    }
}

// ---------------------------------------------------------------------------
extern "C" void kernel_launch(void* const* d_in, const int* in_sizes, int n_in,
                              void* d_out, int out_size, void* d_ws, size_t ws_size,
                              hipStream_t stream) {
    const float* x      = (const float*)d_in[0];
    const float* conv_w = (const float*)d_in[1];
    const float* conv_b = (const float*)d_in[2];
    const float* fc_w   = (const float*)d_in[3];
    const float* fc_b   = (const float*)d_in[4];
    float* out = (float*)d_out;

    const size_t stateN = (size_t)kB * kW * kCH;  // 4,194,304
    unsigned int* hcA   = (unsigned int*)d_ws;
    unsigned int* hcB   = hcA + stateN;
    short* Bp           = (short*)(hcB + stateN);
    float* pxw          = (float*)(Bp + 3 * 512 * 128);
    float* pb           = pxw + 3 * 512;
    float* pooled       = pb + 512;  // [64][128]

    pack_weights<<<768, 256, 0, stream>>>(conv_w, conv_b, Bp, pxw, pb, pooled);

    dim3 grid(kW / 64, 2, kB);
    dim3 block(256);
    // write(t) = t even ? hcB : hcA; read(t) = write(t-1).
    lstm_step<true, false><<<grid, block, 0, stream>>>(
        x, Bp, pxw, pb, hcA, hcB, pooled, 0);
    for (int t = 1; t < kH - 1; ++t) {
        const unsigned int* hi = (t & 1) ? hcB : hcA;
        unsigned int*       ho = (t & 1) ? hcA : hcB;
        lstm_step<false, false><<<grid, block, 0, stream>>>(
            x, Bp, pxw, pb, hi, ho, pooled, t);
    }
    // t = 127 (odd): reads write(126) = hcB; outputs pooled only.
    lstm_step<false, true><<<grid, block, 0, stream>>>(
        x, Bp, pxw, pb, hcB, hcA, pooled, 127);

    fc_final<<<kB, 64, 0, stream>>>(pooled, fc_w, fc_b, out);
}

// Round 14
// 3362.428 us; speedup vs baseline: 1.9987x; 1.0448x over previous
//
#include <hip/hip_runtime.h>
#include <hip/hip_bf16.h>
#include <math.h>

// ConvLSTMClassifier on MI355X — per-step MFMA, 4 blocks/CU, A AND B staged
// via global_load_lds (no VGPR round-trip, no ds_write issue, no extraction).
// gates[b,w,n] = bias[n] + sum_kx x[b,t,w+kx-1]*pxw[kx,n]
//              + sum_kx sum_ic h[b,w+kx-1,ic]*Bp[kx,n,ic],  n = g*128+ch.
// h: bf16 [B][W+2][CH], guard rows w=-1,512 permanently zero -> A staging is
//   1056 global_load_lds(16B) per block with the XOR swizzle baked into the
//   per-lane GLOBAL address (linear LDS dest), zero bounds checks.
// c: bf16 [B][W][CH], epilogue-only.
// Block: 256 thr / 4 waves; tile M=64 x N=256 (4 gates x 64 ch).
// grid (8, 2, 64) = 1024 blocks = 4/CU. B: 24 x 8KB ping-pong stages (r13).
// LDS 33.2 KB/block. 128 launches + fc_final.

constexpr int kB  = 64;
constexpr int kCH = 128;
constexpr int kH  = 128;
constexpr int kW  = 512;
constexpr int kNC = 10;
constexpr int kWP = kW + 2;  // padded h rows (guards at w=-1, w=512)

typedef __attribute__((ext_vector_type(8))) short short8v;
typedef __attribute__((ext_vector_type(4))) float float4v;

__device__ __forceinline__ float fsig(float v) {
    return 1.0f / (1.0f + __expf(-v));
}
__device__ __forceinline__ float ftanh(float v) {
    float e = __expf(2.0f * v);
    return 1.0f - 2.0f / (e + 1.0f);
}
__device__ __forceinline__ float bf_to_f32(unsigned short u) {
    unsigned int t = (unsigned int)u << 16;
    return *reinterpret_cast<float*>(&t);
}
__device__ __forceinline__ unsigned short f32_to_bf(float f) {
    __hip_bfloat16 h = __float2bfloat16(f);
    return *reinterpret_cast<unsigned short*>(&h);
}

// ---------------------------------------------------------------------------
// Weight pack + guard-row zeroing + pooled zeroing.
// ---------------------------------------------------------------------------
__global__ __launch_bounds__(256) void pack_weights(
    const float* __restrict__ conv_w,  // [512][129][3][3]
    const float* __restrict__ conv_b,  // [512]
    short* __restrict__ Bp,            // [3][512][128]
    float* __restrict__ pxw,           // [3][512]
    float* __restrict__ pb,            // [512]
    float* __restrict__ pooled,        // [64][128]
    unsigned short* __restrict__ hA,   // [B][W+2][CH]
    unsigned short* __restrict__ hB)   // [B][W+2][CH]
{
    int idx = blockIdx.x * 256 + threadIdx.x;
    if (idx < 3 * 512 * 128) {
        int ic = idx & 127;
        int oc = (idx >> 7) & 511;
        int kx = idx >> 16;
        float v = conv_w[((oc * 129 + 1 + ic) * 3 + 1) * 3 + kx];
        __hip_bfloat16 hv = __float2bfloat16(v);
        Bp[idx] = *reinterpret_cast<short*>(&hv);
    }
    if (idx < 3 * 512) {
        int oc = idx & 511, kx = idx >> 9;
        pxw[idx] = conv_w[((oc * 129 + 0) * 3 + 1) * 3 + kx];
    }
    if (idx < 512) pb[idx] = conv_b[idx];
    if (idx < kB * kCH) pooled[idx] = 0.0f;
    // zero guard rows (w=-1 -> padded row 0, w=512 -> padded row 513)
    if (idx < kB * 2 * kCH) {
        int b  = idx >> 8;
        int r  = (idx >> 7) & 1;
        int ch = idx & 127;
        size_t off = ((size_t)b * kWP + (r ? (kWP - 1) : 0)) * kCH + ch;
        hA[off] = 0;
        hB[off] = 0;
    }
}

// ---------------------------------------------------------------------------
// One LSTM step. grid = (8 wtiles, 2 cht, 64 b), block = 256 (4 waves).
// ---------------------------------------------------------------------------
template <bool FIRST, bool LAST>
__global__ __launch_bounds__(256, 4) void lstm_step(
    const float* __restrict__ x,              // [B][1][H][W]
    const short* __restrict__ Bp,             // [3][512][128]
    const float* __restrict__ pxw,            // [3][512]
    const float* __restrict__ pb,             // [512]
    const unsigned short* __restrict__ hIn,   // [B][W+2][CH] bf16, guarded
    unsigned short* __restrict__ hOut,        // [B][W+2][CH] bf16, guarded
    const unsigned short* __restrict__ cIn,   // [B][W][CH] bf16
    unsigned short* __restrict__ cOut,        // [B][W][CH] bf16
    float* __restrict__ pooled,               // [B][CH]
    int t)
{
    __shared__ alignas(16) short S[66 * 128];     // h slab, swizzled (16.9 KB)
    __shared__ alignas(16) short Bb[2][128 * 32]; // B ping-pong (2 x 8 KB)
    __shared__ float xs[66];

    const int tid  = threadIdx.x;
    const int lane = tid & 63;
    const int wave = tid >> 6;          // 0..3 = 16-ch slice within cht-half
    const int w0   = blockIdx.x * 64;
    const int cht  = blockIdx.y;        // ch-half
    const int b    = blockIdx.z;

    const int ncol = lane & 15;
    const int krow = lane >> 4;
    const int ch   = cht * 64 + wave * 16 + ncol;  // 0..127

    const size_t hbase = (size_t)b * kWP * kCH;  // padded-h base
    const size_t cbase = (size_t)b * kW * kCH;   // c base

    // B gll source bases (r13-proven): stage row rr, 16B slot sl; k-slot
    // permutation kk baked into the per-lane GLOBAL address; LDS linear.
    int bsrc[2], ldst[2];
#pragma unroll
    for (int cc = 0; cc < 2; ++cc) {
        int rr = wave * 32 + cc * 16 + (lane >> 2);
        int sl = lane & 3;
        int kk = sl ^ ((rr ^ (rr >> 2)) & 3);
        int n0 = (rr >> 6) * 128 + cht * 64 + (rr & 63);
        bsrc[cc] = n0 * 128 + kk * 8;       // shorts
        ldst[cc] = (wave * 2 + cc) * 512;   // shorts
    }

#define B_ISSUE(OFF, BUF)                                                      \
    {                                                                          \
        __builtin_amdgcn_global_load_lds(                                      \
            (const unsigned int*)(Bp + bsrc[0] + (OFF)),                       \
            (unsigned int*)(&Bb[BUF][ldst[0]]), 16, 0, 0);                     \
        __builtin_amdgcn_global_load_lds(                                      \
            (const unsigned int*)(Bp + bsrc[1] + (OFF)),                       \
            (unsigned int*)(&Bb[BUF][ldst[1]]), 16, 0, 0);                     \
    }

    // ---- staging: x strip (VALU path) + A slab & B stage 0 via gll ----
    for (int i = tid; i < 66; i += 256) {
        int w = w0 - 1 + i;
        xs[i] = (w >= 0 && w < kW)
              ? x[((size_t)b * kH + t) * kW + w] : 0.0f;
    }
    if (!FIRST) {
        // A slab: LDS position (row, slot) holds global col = slot^(row&7).
        // 1056 chunks of 16B; linear LDS dest = S + i*16B.
        for (int i = tid; i < 66 * 16; i += 256) {
            int row  = i >> 4, slot = i & 15;
            int col  = slot ^ (row & 7);
            int w    = w0 - 1 + row;            // in [-1, 512]: guards cover
            __builtin_amdgcn_global_load_lds(
                (const unsigned int*)(hIn + hbase + (size_t)(w + 1) * kCH + col * 8),
                (unsigned int*)(S + i * 8), 16, 0, 0);
        }
        B_ISSUE(0, 0)  // stage (kx=0, ks=0, gate-pair 0) -> buf0
    }
    __syncthreads();

    float4v acc[4][4];  // [mfrag][gate]
#pragma unroll
    for (int mf = 0; mf < 4; ++mf)
#pragma unroll
        for (int g = 0; g < 4; ++g)
            acc[mf][g] = float4v{0.f, 0.f, 0.f, 0.f};

    if (!FIRST) {
        const int rswz  = (ncol ^ (ncol >> 2)) & 3;
        const int roff0 = (wave * 16 + ncol) * 32 + (krow ^ rswz) * 8;
        const int roff1 = roff0 + 64 * 32;
        short8v afr[4];

#pragma unroll
        for (int kq = 0; kq < 12; ++kq) {
            const int kx = kq >> 2, ks = kq & 3;
            // consume buf0 (gates 0,1); issue (kq, pair 1) -> buf1
            B_ISSUE(kx * 65536 + ks * 32 + 32768, 1)
#pragma unroll
            for (int mf = 0; mf < 4; ++mf) {
                int srow = mf * 16 + ncol + kx;
                int slot = (ks * 4 + krow) ^ (srow & 7);
                afr[mf] = *reinterpret_cast<const short8v*>(
                    S + srow * 128 + slot * 8);
            }
            {
                short8v bv0 = *reinterpret_cast<const short8v*>(Bb[0] + roff0);
                short8v bv1 = *reinterpret_cast<const short8v*>(Bb[0] + roff1);
#pragma unroll
                for (int mf = 0; mf < 4; ++mf) {
                    acc[mf][0] = __builtin_amdgcn_mfma_f32_16x16x32_bf16(
                        afr[mf], bv0, acc[mf][0], 0, 0, 0);
                    acc[mf][1] = __builtin_amdgcn_mfma_f32_16x16x32_bf16(
                        afr[mf], bv1, acc[mf][1], 0, 0, 0);
                }
            }
            __syncthreads();
            // consume buf1 (gates 2,3); issue (kq+1, pair 0) -> buf0
            if (kq < 11) {
                const int kx2 = (kq + 1) >> 2, ks2 = (kq + 1) & 3;
                B_ISSUE(kx2 * 65536 + ks2 * 32, 0)
            }
            {
                short8v bv2 = *reinterpret_cast<const short8v*>(Bb[1] + roff0);
                short8v bv3 = *reinterpret_cast<const short8v*>(Bb[1] + roff1);
#pragma unroll
                for (int mf = 0; mf < 4; ++mf) {
                    acc[mf][2] = __builtin_amdgcn_mfma_f32_16x16x32_bf16(
                        afr[mf], bv2, acc[mf][2], 0, 0, 0);
                    acc[mf][3] = __builtin_amdgcn_mfma_f32_16x16x32_bf16(
                        afr[mf], bv3, acc[mf][3], 0, 0, 0);
                }
            }
            __syncthreads();
        }
    }
#undef B_ISSUE

    // ---- epilogue (r10-proven math; c now 2B, h written to padded buf) ----
    float wxk[4][3], bia[4];
#pragma unroll
    for (int g = 0; g < 4; ++g) {
        bia[g] = pb[g * 128 + ch];
#pragma unroll
        for (int kx = 0; kx < 3; ++kx)
            wxk[g][kx] = pxw[kx * 512 + g * 128 + ch];
    }

    float psum = 0.0f;
#pragma unroll
    for (int mf = 0; mf < 4; ++mf) {
        unsigned short cu[4];
        if (!FIRST) {
#pragma unroll
            for (int r = 0; r < 4; ++r) {
                int m = mf * 16 + krow * 4 + r;
                cu[r] = cIn[cbase + (size_t)(w0 + m) * kCH + ch];
            }
        }
#pragma unroll
        for (int r = 0; r < 4; ++r) {
            int m = mf * 16 + krow * 4 + r;
            float xm = xs[m], xc = xs[m + 1], xp = xs[m + 2];
            float v0 = acc[mf][0][r] + bia[0] + xm * wxk[0][0] + xc * wxk[0][1] + xp * wxk[0][2];
            float v1 = acc[mf][1][r] + bia[1] + xm * wxk[1][0] + xc * wxk[1][1] + xp * wxk[1][2];
            float v2 = acc[mf][2][r] + bia[2] + xm * wxk[2][0] + xc * wxk[2][1] + xp * wxk[2][2];
            float v3 = acc[mf][3][r] + bia[3] + xm * wxk[3][0] + xc * wxk[3][1] + xp * wxk[3][2];
            float cprev = FIRST ? 0.0f : bf_to_f32(cu[r]);
            float si = fsig(v0);
            float sf = fsig(v1);
            float tg = ftanh(v2);
            float so = fsig(v3);
            float cn = sf * cprev + si * tg;
            float hn = so * ftanh(cn);
            if (LAST) {
                psum += hn;
            } else {
                hOut[hbase + (size_t)(w0 + m + 1) * kCH + ch] = f32_to_bf(hn);
                cOut[cbase + (size_t)(w0 + m) * kCH + ch]     = f32_to_bf(cn);
            }
        }
    }

    if (LAST) {
        psum += __shfl_xor(psum, 16, 64);
        psum += __shfl_xor(psum, 32, 64);
        if (krow == 0) atomicAdd(&pooled[b * kCH + ch], psum);
    }
}

// ---------------------------------------------------------------------------
// Final FC from pooled sums. grid = B, block = 64.
// ---------------------------------------------------------------------------
__global__ __launch_bounds__(64) void fc_final(
    const float* __restrict__ pooled,  // [B][CH] raw sums over W
    const float* __restrict__ fc_w,    // [NC][CH]
    const float* __restrict__ fc_b,    // [NC]
    float* __restrict__ out)           // [B][NC]
{
    int b = blockIdx.x, nc = threadIdx.x;
    if (nc < kNC) {
        float s = 0.0f;
        for (int k = 0; k < kCH; ++k)
            s = fmaf(pooled[b * kCH + k], fc_w[nc * kCH + k], s);
        out[b * kNC + nc] = fc_b[nc] + s * (1.0f / kW);
    }
}

// ---------------------------------------------------------------------------
extern "C" void kernel_launch(void* const* d_in, const int* in_sizes, int n_in,
                              void* d_out, int out_size, void* d_ws, size_t ws_size,
                              hipStream_t stream) {
    const float* x      = (const float*)d_in[0];
    const float* conv_w = (const float*)d_in[1];
    const float* conv_b = (const float*)d_in[2];
    const float* fc_w   = (const float*)d_in[3];
    const float* fc_b   = (const float*)d_in[4];
    float* out = (float*)d_out;

    const size_t hN = (size_t)kB * kWP * kCH;  // 4,210,688 (padded h)
    const size_t cN = (size_t)kB * kW * kCH;   // 4,194,304
    unsigned short* hA = (unsigned short*)d_ws;
    unsigned short* hB = hA + hN;
    unsigned short* cA = hB + hN;
    unsigned short* cB = cA + cN;
    short* Bp          = (short*)(cB + cN);
    float* pxw         = (float*)(Bp + 3 * 512 * 128);
    float* pb          = pxw + 3 * 512;
    float* pooled      = pb + 512;  // [64][128]

    pack_weights<<<768, 256, 0, stream>>>(conv_w, conv_b, Bp, pxw, pb, pooled,
                                          hA, hB);

    dim3 grid(kW / 64, 2, kB);
    dim3 block(256);
    // write(t) = t even ? (hB,cB) : (hA,cA); read(t) = write(t-1).
    lstm_step<true, false><<<grid, block, 0, stream>>>(
        x, Bp, pxw, pb, hA, hB, cA, cB, pooled, 0);
    for (int t = 1; t < kH - 1; ++t) {
        const unsigned short* hi = (t & 1) ? hB : hA;
        unsigned short*       ho = (t & 1) ? hA : hB;
        const unsigned short* ci = (t & 1) ? cB : cA;
        unsigned short*       co = (t & 1) ? cA : cB;
        lstm_step<false, false><<<grid, block, 0, stream>>>(
            x, Bp, pxw, pb, hi, ho, ci, co, pooled, t);
    }
    // t = 127 (odd): reads write(126) = (hB,cB); outputs pooled only.
    lstm_step<false, true><<<grid, block, 0, stream>>>(
        x, Bp, pxw, pb, hB, hA, cB, cA, pooled, 127);

    fc_final<<<kB, 64, 0, stream>>>(pooled, fc_w, fc_b, out);
}